// Round 1
// baseline (500.291 us; speedup 1.0000x reference)
//
#include <hip/hip_runtime.h>
#include <math.h>

#define NUM_CLASSES 81
#define WAVES_PER_BLOCK 4

__global__ __launch_bounds__(256) void postproc_kernel(
    const float* __restrict__ logits,
    const float* __restrict__ box_reg,
    const float* __restrict__ prop,
    const int* __restrict__ img_w_p,
    const int* __restrict__ img_h_p,
    float* __restrict__ out_boxes,
    float* __restrict__ out_scores,
    int N)
{
    const int wave = threadIdx.x >> 6;
    const int lane = threadIdx.x & 63;
    const int row  = blockIdx.x * WAVES_PER_BLOCK + wave;
    if (row >= N) return;

    const float wmax = (float)(*img_w_p) - 1.0f;
    const float hmax = (float)(*img_h_p) - 1.0f;

    // ---- decode box (wave-uniform: all lanes compute the same values) ----
    const float b0 = prop[row * 4 + 0];
    const float b1 = prop[row * 4 + 1];
    const float b2 = prop[row * 4 + 2];
    const float b3 = prop[row * 4 + 3];
    const float r0 = box_reg[row * 4 + 0];
    const float r1 = box_reg[row * 4 + 1];
    const float r2 = box_reg[row * 4 + 2];
    const float r3 = box_reg[row * 4 + 3];

    const float BBOX_XFORM_CLIP = 4.135166556742356f; // log(1000/16)
    const float w  = b2 - b0 + 1.0f;
    const float h  = b3 - b1 + 1.0f;
    const float cx = b0 + 0.5f * w;
    const float cy = b1 + 0.5f * h;
    const float dx = r0 / 10.0f;
    const float dy = r1 / 10.0f;
    const float dw = fminf(r2 / 5.0f, BBOX_XFORM_CLIP);
    const float dh = fminf(r3 / 5.0f, BBOX_XFORM_CLIP);
    const float px = dx * w + cx;
    const float py = dy * h + cy;
    const float pw = expf(dw) * w;
    const float ph = expf(dh) * h;
    const float x1 = fminf(fmaxf(px - 0.5f * pw, 0.0f), wmax);
    const float y1 = fminf(fmaxf(py - 0.5f * ph, 0.0f), hmax);
    const float x2 = fminf(fmaxf(px + 0.5f * pw - 1.0f, 0.0f), wmax);
    const float y2 = fminf(fmaxf(py + 0.5f * ph - 1.0f, 0.0f), hmax);
    const float4 box = make_float4(x1, y1, x2, y2);

    // ---- softmax over C=81 within one wave ----
    const float* lrow = logits + (size_t)row * NUM_CLASSES;
    const bool has2 = (lane < NUM_CLASSES - 64);  // lanes 0..16 hold a 2nd elem
    float v0 = lrow[lane];
    float v1 = has2 ? lrow[64 + lane] : -INFINITY;

    float m = fmaxf(v0, v1);
    #pragma unroll
    for (int off = 32; off > 0; off >>= 1)
        m = fmaxf(m, __shfl_xor(m, off));

    float e0 = expf(v0 - m);
    float e1 = has2 ? expf(v1 - m) : 0.0f;
    float s = e0 + e1;
    #pragma unroll
    for (int off = 32; off > 0; off >>= 1)
        s += __shfl_xor(s, off);

    // ---- writes: 81 float4 box copies + 81 scores, coalesced ----
    float4* brow = reinterpret_cast<float4*>(out_boxes + (size_t)row * (NUM_CLASSES * 4));
    float*  srow = out_scores + (size_t)row * NUM_CLASSES;

    brow[lane] = box;
    srow[lane] = e0 / s;
    if (has2) {
        brow[64 + lane] = box;
        srow[64 + lane] = e1 / s;
    }
}

extern "C" void kernel_launch(void* const* d_in, const int* in_sizes, int n_in,
                              void* d_out, int out_size, void* d_ws, size_t ws_size,
                              hipStream_t stream) {
    const float* logits  = (const float*)d_in[0];
    const float* box_reg = (const float*)d_in[1];
    const float* prop    = (const float*)d_in[2];
    const int*   img_w_p = (const int*)d_in[3];
    const int*   img_h_p = (const int*)d_in[4];

    const int N = in_sizes[1] / 4;  // box_regression is (N,4)

    float* out_boxes  = (float*)d_out;
    float* out_scores = out_boxes + (size_t)N * NUM_CLASSES * 4;

    const int blocks = (N + WAVES_PER_BLOCK - 1) / WAVES_PER_BLOCK;
    postproc_kernel<<<blocks, 256, 0, stream>>>(
        logits, box_reg, prop, img_w_p, img_h_p, out_boxes, out_scores, N);
}